// Round 1
// baseline (5498.112 us; speedup 1.0000x reference)
//
#include <hip/hip_runtime.h>
#include <math.h>

#define EPS 1e-7f

constexpr int Nn = 4, Cc = 3, Hh = 1080, Ww = 1920;
constexpr int HW = Hh * Ww;
constexpr int TOTAL = Nn * HW;

// ---------------- fast path: NHWC 4-channel accumulator in d_ws ----------------

__global__ __launch_bounds__(256) void splat_nhwc(
    const float* __restrict__ tenIn, const float* __restrict__ tenFlow,
    const float* __restrict__ tenMetric, float* __restrict__ acc)
{
    int idx = blockIdx.x * 256 + threadIdx.x;
    if (idx >= TOTAL) return;
    int n = idx / HW;
    int p = idx - n * HW;
    int y = p / Ww;
    int x = p - y * Ww;

    float fx = (float)x + tenFlow[(n * 2 + 0) * HW + p];
    float fy = (float)y + tenFlow[(n * 2 + 1) * HW + p];
    if (!isfinite(fx) || !isfinite(fy)) return;              // ref: all weights 0
    // no corner can be in-bounds outside this range; also guards int-cast UB
    if (!(fx > -1.0f && fx < (float)Ww && fy > -1.0f && fy < (float)Hh)) return;

    float m = expf(tenMetric[n * HW + p]);
    float v0 = tenIn[(n * 3 + 0) * HW + p] * m;
    float v1 = tenIn[(n * 3 + 1) * HW + p] * m;
    float v2 = tenIn[(n * 3 + 2) * HW + p] * m;

    float flx = floorf(fx), fly = floorf(fy);
    int x0 = (int)flx, y0 = (int)fly;
    float wx1 = fx - flx, wx0 = 1.0f - wx1;
    float wy1 = fy - fly, wy0 = 1.0f - wy1;

    bool vx0 = (x0 >= 0), vx1 = (x0 + 1 < Ww);
    bool vy0 = (y0 >= 0), vy1 = (y0 + 1 < Hh);

    int rowbase = (n * Hh + y0) * Ww + x0;   // pixel index of NW corner

#define CORNER(PIX, WGT)                                   \
    do {                                                   \
        float w_ = (WGT);                                  \
        float* a_ = acc + (size_t)(PIX) * 4;               \
        atomicAdd(a_ + 0, v0 * w_);                        \
        atomicAdd(a_ + 1, v1 * w_);                        \
        atomicAdd(a_ + 2, v2 * w_);                        \
        atomicAdd(a_ + 3, m * w_);                         \
    } while (0)

    if (vx0 && vy0) CORNER(rowbase,           wx0 * wy0);
    if (vx1 && vy0) CORNER(rowbase + 1,       wx1 * wy0);
    if (vx0 && vy1) CORNER(rowbase + Ww,      wx0 * wy1);
    if (vx1 && vy1) CORNER(rowbase + Ww + 1,  wx1 * wy1);
#undef CORNER
}

__global__ __launch_bounds__(256) void normalize_nhwc(
    const float* __restrict__ acc, float* __restrict__ out)
{
    int idx = blockIdx.x * 256 + threadIdx.x;
    if (idx >= TOTAL) return;
    int n = idx / HW;
    int p = idx - n * HW;
    float4 a = ((const float4*)acc)[idx];
    float d = a.w + EPS;
    out[(n * 3 + 0) * HW + p] = a.x / d;
    out[(n * 3 + 1) * HW + p] = a.y / d;
    out[(n * 3 + 2) * HW + p] = a.z / d;
}

// ---------------- fallback: NCHW channels in d_out, weight plane in d_ws ----------------

__global__ __launch_bounds__(256) void splat_nchw(
    const float* __restrict__ tenIn, const float* __restrict__ tenFlow,
    const float* __restrict__ tenMetric, float* __restrict__ out,
    float* __restrict__ wacc)
{
    int idx = blockIdx.x * 256 + threadIdx.x;
    if (idx >= TOTAL) return;
    int n = idx / HW;
    int p = idx - n * HW;
    int y = p / Ww;
    int x = p - y * Ww;

    float fx = (float)x + tenFlow[(n * 2 + 0) * HW + p];
    float fy = (float)y + tenFlow[(n * 2 + 1) * HW + p];
    if (!isfinite(fx) || !isfinite(fy)) return;
    if (!(fx > -1.0f && fx < (float)Ww && fy > -1.0f && fy < (float)Hh)) return;

    float m = expf(tenMetric[n * HW + p]);
    float v0 = tenIn[(n * 3 + 0) * HW + p] * m;
    float v1 = tenIn[(n * 3 + 1) * HW + p] * m;
    float v2 = tenIn[(n * 3 + 2) * HW + p] * m;

    float flx = floorf(fx), fly = floorf(fy);
    int x0 = (int)flx, y0 = (int)fly;
    float wx1 = fx - flx, wx0 = 1.0f - wx1;
    float wy1 = fy - fly, wy0 = 1.0f - wy1;

    bool vx0 = (x0 >= 0), vx1 = (x0 + 1 < Ww);
    bool vy0 = (y0 >= 0), vy1 = (y0 + 1 < Hh);

    int rowbase = y0 * Ww + x0;

#define CORNER(PIX, WGT)                                           \
    do {                                                           \
        float w_ = (WGT);                                          \
        int pp_ = (PIX);                                           \
        atomicAdd(out + (n * 3 + 0) * HW + pp_, v0 * w_);          \
        atomicAdd(out + (n * 3 + 1) * HW + pp_, v1 * w_);          \
        atomicAdd(out + (n * 3 + 2) * HW + pp_, v2 * w_);          \
        atomicAdd(wacc + n * HW + pp_, m * w_);                    \
    } while (0)

    if (vx0 && vy0) CORNER(rowbase,          wx0 * wy0);
    if (vx1 && vy0) CORNER(rowbase + 1,      wx1 * wy0);
    if (vx0 && vy1) CORNER(rowbase + Ww,     wx0 * wy1);
    if (vx1 && vy1) CORNER(rowbase + Ww + 1, wx1 * wy1);
#undef CORNER
}

__global__ __launch_bounds__(256) void normalize_nchw(
    const float* __restrict__ wacc, float* __restrict__ out)
{
    int idx = blockIdx.x * 256 + threadIdx.x;
    if (idx >= TOTAL) return;
    int n = idx / HW;
    int p = idx - n * HW;
    float d = wacc[n * HW + p] + EPS;
    out[(n * 3 + 0) * HW + p] /= d;
    out[(n * 3 + 1) * HW + p] /= d;
    out[(n * 3 + 2) * HW + p] /= d;
}

extern "C" void kernel_launch(void* const* d_in, const int* in_sizes, int n_in,
                              void* d_out, int out_size, void* d_ws, size_t ws_size,
                              hipStream_t stream) {
    const float* tenIn     = (const float*)d_in[0];
    const float* tenFlow   = (const float*)d_in[1];
    const float* tenMetric = (const float*)d_in[2];
    float* out = (float*)d_out;

    const int threads = 256;
    const int blocks  = (TOTAL + threads - 1) / threads;

    const size_t accBytesNHWC = (size_t)TOTAL * 4 * sizeof(float);   // ~132.7 MB
    const size_t accBytesW    = (size_t)TOTAL * sizeof(float);       // ~33.2 MB

    if (ws_size >= accBytesNHWC) {
        float* acc = (float*)d_ws;
        hipMemsetAsync(d_ws, 0, accBytesNHWC, stream);
        splat_nhwc<<<blocks, threads, 0, stream>>>(tenIn, tenFlow, tenMetric, acc);
        normalize_nhwc<<<blocks, threads, 0, stream>>>(acc, out);
    } else {
        // fallback: accumulate channels directly in d_out, weight plane in ws
        float* wacc = (float*)d_ws;
        hipMemsetAsync(d_out, 0, (size_t)out_size * sizeof(float), stream);
        hipMemsetAsync(d_ws, 0, accBytesW, stream);
        splat_nchw<<<blocks, threads, 0, stream>>>(tenIn, tenFlow, tenMetric, out, wacc);
        normalize_nchw<<<blocks, threads, 0, stream>>>((const float*)d_ws, out);
    }
}

// Round 2
// 884.355 us; speedup vs baseline: 6.2171x; 6.2171x over previous
//
#include <hip/hip_runtime.h>
#include <math.h>

#define EPS 1e-7f

constexpr int Nn = 4, Hh = 1080, Ww = 1920;
constexpr int HW = Hh * Ww;
constexpr int TOTAL = Nn * HW;

constexpr int TW = 32, TH = 32;          // output tile
constexpr int TXN = 60, TYN = 34;        // tiles per image (60*32=1920 exact, 34*32=1088>1080)
constexpr int HALO = 6;
constexpr float NEAR_MAX = 5.0f;         // = HALO-1; |flow|<=5 -> footprint within halo
constexpr int WINW = TW + 2 * HALO;      // 44
constexpr int WINH = TH + 2 * HALO;      // 44
constexpr int WINSZ = WINW * WINH;       // 1936
constexpr int NTILES = Nn * TYN * TXN;   // 8160
constexpr size_t FACC_BYTES = (size_t)TOTAL * 4 * sizeof(float);   // 132.7 MB
constexpr size_t FLAG_BYTES = (size_t)NTILES * sizeof(int);        // ~32.6 KB

// ---------------- pass 1: rare far sources (|flow|>5) -> global atomic scatter ----------------

__global__ __launch_bounds__(256) void far_scatter(
    const float* __restrict__ tenIn, const float* __restrict__ tenFlow,
    const float* __restrict__ tenMetric, float* __restrict__ facc,
    int* __restrict__ flags, int haveFlags)
{
    int idx = blockIdx.x * 256 + threadIdx.x;
    if (idx >= TOTAL) return;
    int n = idx / HW;
    int p = idx - n * HW;

    float fxv = tenFlow[(n * 2 + 0) * HW + p];
    float fyv = tenFlow[(n * 2 + 1) * HW + p];
    // near (both |f|<=5) or NaN -> handled by gather / skipped
    if (!(fabsf(fxv) > NEAR_MAX || fabsf(fyv) > NEAR_MAX)) return;

    int y = p / Ww;
    int x = p - y * Ww;
    float fx = (float)x + fxv;
    float fy = (float)y + fyv;
    if (!isfinite(fx) || !isfinite(fy)) return;
    if (!(fx > -1.0f && fx < (float)Ww && fy > -1.0f && fy < (float)Hh)) return;

    float m  = expf(tenMetric[n * HW + p]);
    float v0 = tenIn[(n * 3 + 0) * HW + p] * m;
    float v1 = tenIn[(n * 3 + 1) * HW + p] * m;
    float v2 = tenIn[(n * 3 + 2) * HW + p] * m;

    float flx = floorf(fx), fly = floorf(fy);
    int x0 = (int)flx, y0 = (int)fly;
    float wx1 = fx - flx, wx0 = 1.0f - wx1;
    float wy1 = fy - fly, wy0 = 1.0f - wy1;

#define FCORNER(CX, CY, WGT)                                              \
    do {                                                                  \
        int cx_ = (CX), cy_ = (CY);                                       \
        if (cx_ >= 0 && cx_ < Ww && cy_ >= 0 && cy_ < Hh) {               \
            float w_ = (WGT);                                             \
            size_t cell_ = (size_t)n * HW + (size_t)cy_ * Ww + cx_;       \
            float* a_ = facc + cell_ * 4;                                 \
            atomicAdd(a_ + 0, v0 * w_);                                   \
            atomicAdd(a_ + 1, v1 * w_);                                   \
            atomicAdd(a_ + 2, v2 * w_);                                   \
            atomicAdd(a_ + 3, m * w_);                                    \
            if (haveFlags) {                                              \
                int t_ = (n * TYN + cy_ / TH) * TXN + cx_ / TW;           \
                atomicOr(flags + t_, 1);                                  \
            }                                                             \
        }                                                                 \
    } while (0)

    FCORNER(x0,     y0,     wx0 * wy0);
    FCORNER(x0 + 1, y0,     wx1 * wy0);
    FCORNER(x0,     y0 + 1, wx0 * wy1);
    FCORNER(x0 + 1, y0 + 1, wx1 * wy1);
#undef FCORNER
}

// ---------------- pass 2: tile gather, LDS accumulation, fused normalize ----------------

__global__ __launch_bounds__(256) void gather_splat(
    const float* __restrict__ tenIn, const float* __restrict__ tenFlow,
    const float* __restrict__ tenMetric, const float4* __restrict__ facc,
    const int* __restrict__ flags, int dirtyAll, float* __restrict__ out)
{
    // SoA accumulator: accS[c*1024 + cell] to spread LDS banks
    __shared__ float accS[4 * TW * TH];

    const int tx = blockIdx.x, ty = blockIdx.y, n = blockIdx.z;
    const int tX = tx * TW, tY = ty * TH;
    const int tid = threadIdx.x;

    for (int j = tid; j < 4 * TW * TH; j += 256) accS[j] = 0.0f;
    __syncthreads();

    const float* __restrict__ f0 = tenFlow   + (size_t)(n * 2 + 0) * HW;
    const float* __restrict__ f1 = tenFlow   + (size_t)(n * 2 + 1) * HW;
    const float* __restrict__ mp = tenMetric + (size_t)n * HW;
    const float* __restrict__ i0 = tenIn + (size_t)(n * 3 + 0) * HW;
    const float* __restrict__ i1 = tenIn + (size_t)(n * 3 + 1) * HW;
    const float* __restrict__ i2 = tenIn + (size_t)(n * 3 + 2) * HW;

    for (int i = tid; i < WINSZ; i += 256) {
        int wy = i / WINW;
        int wx = i - wy * WINW;
        int sy = tY - HALO + wy;
        int sx = tX - HALO + wx;
        if (sx < 0 || sx >= Ww || sy < 0 || sy >= Hh) continue;
        int p = sy * Ww + sx;

        float fxv = f0[p], fyv = f1[p];
        // near only (NaN fails -> skip; far handled by pass 1)
        if (!(fabsf(fxv) <= NEAR_MAX && fabsf(fyv) <= NEAR_MAX)) continue;

        float fx = (float)sx + fxv;       // in [-5, 1924] -> safe int cast
        float fy = (float)sy + fyv;
        float flx = floorf(fx), fly = floorf(fy);
        int lx0 = (int)flx - tX;          // NW corner, tile-local
        int ly0 = (int)fly - tY;
        // footprint {lx0,lx0+1}x{ly0,ly0+1} must intersect [0,TW)x[0,TH)
        if (lx0 < -1 || lx0 > TW - 1 || ly0 < -1 || ly0 > TH - 1) continue;

        float m  = expf(mp[p]);
        float v0 = i0[p] * m;
        float v1 = i1[p] * m;
        float v2 = i2[p] * m;

        float wx1 = fx - flx, wx0 = 1.0f - wx1;
        float wy1 = fy - fly, wy0 = 1.0f - wy1;

#define LCORNER(LX, LY, WGT)                                              \
    do {                                                                  \
        int lx_ = (LX), ly_ = (LY);                                       \
        if (lx_ >= 0 && lx_ < TW && ly_ >= 0 && ly_ < TH &&               \
            (tY + ly_) < Hh) {                                            \
            float w_ = (WGT);                                             \
            int cell_ = ly_ * TW + lx_;                                   \
            atomicAdd(&accS[cell_],            v0 * w_);                  \
            atomicAdd(&accS[1024 + cell_],     v1 * w_);                  \
            atomicAdd(&accS[2048 + cell_],     v2 * w_);                  \
            atomicAdd(&accS[3072 + cell_],     m * w_);                   \
        }                                                                 \
    } while (0)

        LCORNER(lx0,     ly0,     wx0 * wy0);
        LCORNER(lx0 + 1, ly0,     wx1 * wy0);
        LCORNER(lx0,     ly0 + 1, wx0 * wy1);
        LCORNER(lx0 + 1, ly0 + 1, wx1 * wy1);
#undef LCORNER
    }
    __syncthreads();

    bool dirty = dirtyAll || (flags && (flags[(n * TYN + ty) * TXN + tx] != 0));

    for (int j = tid; j < TW * TH; j += 256) {
        int ly = j / TW;
        int lx = j - ly * TW;
        int gy = tY + ly;
        int gx = tX + lx;
        if (gy >= Hh) continue;
        size_t cell = (size_t)n * HW + (size_t)gy * Ww + gx;

        float a0 = accS[j];
        float a1 = accS[1024 + j];
        float a2 = accS[2048 + j];
        float a3 = accS[3072 + j];
        if (dirty) {
            float4 f = facc[cell];
            a0 += f.x; a1 += f.y; a2 += f.z; a3 += f.w;
        }
        float d = a3 + EPS;
        size_t pix = (size_t)gy * Ww + gx;
        out[((size_t)n * 3 + 0) * HW + pix] = a0 / d;
        out[((size_t)n * 3 + 1) * HW + pix] = a1 / d;
        out[((size_t)n * 3 + 2) * HW + pix] = a2 / d;
    }
}

extern "C" void kernel_launch(void* const* d_in, const int* in_sizes, int n_in,
                              void* d_out, int out_size, void* d_ws, size_t ws_size,
                              hipStream_t stream) {
    const float* tenIn     = (const float*)d_in[0];
    const float* tenFlow   = (const float*)d_in[1];
    const float* tenMetric = (const float*)d_in[2];
    float* out = (float*)d_out;

    float* facc = (float*)d_ws;
    int haveFlags = (ws_size >= FACC_BYTES + FLAG_BYTES) ? 1 : 0;
    int* flags = haveFlags ? (int*)((char*)d_ws + FACC_BYTES) : nullptr;

    // zero far accumulator (+ flags if present) — poison otherwise
    hipMemsetAsync(d_ws, 0, haveFlags ? (FACC_BYTES + FLAG_BYTES) : FACC_BYTES, stream);

    far_scatter<<<(TOTAL + 255) / 256, 256, 0, stream>>>(
        tenIn, tenFlow, tenMetric, facc, flags, haveFlags);

    dim3 grid(TXN, TYN, Nn);
    gather_splat<<<grid, 256, 0, stream>>>(
        tenIn, tenFlow, tenMetric, (const float4*)facc, flags,
        haveFlags ? 0 : 1, out);
}